// Round 17
// baseline (94.090 us; speedup 1.0000x reference)
//
#include <hip/hip_runtime.h>
#include <hip/hip_bf16.h>
#include <float.h>

#define DI   64
#define DOUT 62
#define CI   3
#define CO   16
#define NB   16
constexpr int SP    = DOUT * DOUT * DOUT;    // 238328
constexpr int SP64  = DOUT * DOUT * 64;      // padded per-channel y extent
constexpr int HT    = 31;                    // h-tiles of 2
constexpr int DT    = 16;                    // d-tiles of 4
constexpr int NPART = HT * DT;               // 496
constexpr int RSTR  = 34;                    // slab dword row stride
constexpr int PHD   = 72 * RSTR;             // 2448 dwords per phase

typedef __attribute__((ext_vector_type(8))) short bf16x8;
typedef __attribute__((ext_vector_type(4))) float f32x4;

// Module BSS scratch (fully rewritten every call)
__device__ float g_psum[NB * CO * NPART];
__device__ float g_psq [NB * CO * NPART];
__device__ float g_stats[NB * CO * 2];       // (A, B') per (n,c): z = a*A + B'
__device__ uint4 g_wb4[4 * 64];              // per-lane B fragments
__device__ uint2 g_rt [4 * 64];              // per-lane row offsets (x RSTR) for gA,gB

__device__ __forceinline__ unsigned short f2bf(float v) {
    __hip_bfloat16 h = __float2bfloat16(v);
    return __builtin_bit_cast(unsigned short, h);
}
__device__ __forceinline__ unsigned int pk2(float lo, float hi) {
    return (unsigned int)f2bf(lo) | ((unsigned int)f2bf(hi) << 16);
}

// K-mapping: MFMA t, lane-quarter q -> pair P = t*4+q -> groups (2P, 2P+1).
// Also per-lane slab-row-offset table: baseRow(g) = i*24+kd*4+kh (x RSTR).
__global__ void reorg_w_kernel(const float* __restrict__ w)
{
    unsigned int* dst = (unsigned int*)g_wb4;
    for (int dwi = threadIdx.x; dwi < 4 * 64 * 4; dwi += 256) {
        const int t    = dwi >> 8;
        const int lane = (dwi >> 2) & 63;
        const int dw   = dwi & 3;
        const int o    = lane & 15, q = lane >> 4;
        const int P    = t * 4 + q;
        unsigned int u = 0;
        for (int half = 0; half < 2; ++half) {
            const int j = dw * 2 + half;
            const int g = (j < 4) ? (2 * P) : (2 * P + 1);
            const int r = j & 3;
            float val = 0.f;
            if (g <= 26 && r < 3) {
                const int i = g / 9, kd = (g % 9) / 3, kh = g % 3;
                val = w[o * 81 + i * 27 + kd * 9 + kh * 3 + r];
            }
            u |= ((unsigned int)f2bf(val)) << (16 * half);
        }
        dst[dwi] = u;
    }
    if (threadIdx.x < 256) {
        const int t = threadIdx.x >> 6, lane = threadIdx.x & 63;
        const int q = lane >> 4, P = t * 4 + q;
        uint2 rt;
        const int gA = 2 * P, gB = 2 * P + 1;
        rt.x = (gA <= 26) ? ((gA / 9) * 24 + ((gA % 9) / 3) * 4 + gA % 3) * RSTR : 0;
        rt.y = (gB <= 26) ? ((gB / 9) * 24 + ((gB % 9) / 3) * 4 + gB % 3) * RSTR : 0;
        g_rt[t * 64 + lane] = rt;
    }
}

// ---------------------------------------------------------------------------
// MFMA conv. Block (64,8): wave ty -> (dl=ty>>1, hl=ty&1). Position w = 4m+wt.
// Staging: fp32 float2 loads (coalesced, fused cvt), per-phase b32 LDS writes
// (lanes cover t=0..31 -> conflict-free; R16's b64 writes were all-even-bank).
// A-gather: aligned ds_read_b64. Bias/m deferred: raw-acc stats & y.
// MODE 0: stats only. 1: stats + y[n][ch][d][h][64] bf16. 2: recompute -> out.
// ---------------------------------------------------------------------------
template <int MODE>
__global__ __launch_bounds__(512) void conv_mfma_kernel(
    const float* __restrict__ x, const float* __restrict__ m,
    unsigned int* __restrict__ y32, float* __restrict__ out)
{
    __shared__ unsigned int xs[4 * PHD];     // 39168 B
    __shared__ float redS[8][CO], redQ[8][CO];

    const int lane = threadIdx.x, ty = threadIdx.y;
    const int h0 = blockIdx.x * 2, d0 = blockIdx.y * 4, n = blockIdx.z;
    const int tid = ty * 64 + lane;

    // ---- stage 4 phase-interleavings; one dword column per lane-iter ----
    const int row0 = tid >> 5;               // 0..15
    const int tcol = tid & 31;
#pragma unroll
    for (int k = 0; k < 5; ++k) {
        const int row = row0 + k * 16;       // 0..79
        const int rc  = min(row, 71);
        const int i = rc / 24, rm = rc % 24, p = rm >> 2, hr = rm & 3;
        const int dg = min(d0 + p, DI - 1);
        const float2 f = *(const float2*)(x +
            ((((size_t)n * CI + i) * DI + dg) * DI + (h0 + hr)) * 64 + 2 * tcol);
        const unsigned u0 = pk2(f.x, f.y);
        const unsigned u1 = __shfl_down(u0, 1);   // dword t+1 (junk at col 31: masked outputs)
        const unsigned u2 = __shfl_down(u0, 2);   // dword t+2
        if (row < 72) {
            unsigned int* dp = xs + row * RSTR + tcol;
            dp[0 * PHD] = u0;
            dp[1 * PHD] = __builtin_amdgcn_alignbit(u1, u0, 16);
            dp[2 * PHD] = u1;
            dp[3 * PHD] = __builtin_amdgcn_alignbit(u2, u1, 16);
        }
    }
    __syncthreads();

    const int c = lane & 15, q = lane >> 4;
    const int dl = ty >> 1, hl = ty & 1;
    const int offr = ((dl << 2) + hl) * RSTR;

    // Resident B fragments + A-gather addresses (dword units)
    bf16x8 wf[4];
    int aA[4], aB[4];
#pragma unroll
    for (int t = 0; t < 4; ++t) {
        wf[t] = __builtin_bit_cast(bf16x8, g_wb4[t * 64 + lane]);
        const uint2 rt = g_rt[t * 64 + lane];
        aA[t] = (int)rt.x + offr + 2 * c;
        aB[t] = (int)rt.y + offr + 2 * c;
    }

    const float mc = m[c];
    float A = 0.f, Bp = 0.f;
    if (MODE == 2) {
        A  = g_stats[(n * CO + c) * 2 + 0];
        Bp = g_stats[(n * CO + c) * 2 + 1];
    }

    const int d = d0 + dl, h = h0 + hl;
    const bool dvalid = d < DOUT;
    float sS = 0.f, qS = 0.f;

    if (dvalid) {
        f32x4 acc[4];
#pragma unroll
        for (int wt = 0; wt < 4; ++wt) {
            f32x4 a = {0.f, 0.f, 0.f, 0.f};
#pragma unroll
            for (int t = 0; t < 4; ++t) {
                const uint2 lo = *(const uint2*)(xs + wt * PHD + aA[t]);
                const uint2 hi = *(const uint2*)(xs + wt * PHD + aB[t]);
                uint4 av;
                av.x = lo.x; av.y = lo.y; av.z = hi.x; av.w = hi.y;
                a = __builtin_amdgcn_mfma_f32_16x16x32_bf16(
                        __builtin_bit_cast(bf16x8, av), wf[t], a, 0, 0, 0);
            }
            acc[wt] = a;
        }

        if (MODE == 2) {
            const size_t spb = (size_t)(d * DOUT + h) * DOUT + 16 * q;
#pragma unroll
            for (int reg = 0; reg < 4; ++reg)
#pragma unroll
                for (int wt = 0; wt < 4; ++wt) {
                    const int p = reg * 4 + wt;
                    float z = fminf(fmaxf(fmaf(acc[wt][reg], A, Bp), -1.f), 1.f) * mc;
                    z = fmaxf(z, __shfl_xor(z, 1));
                    z = fmaxf(z, __shfl_xor(z, 2));
                    z = fmaxf(z, __shfl_xor(z, 4));
                    z = fmaxf(z, __shfl_xor(z, 8));
                    if (c == p && (p < 14 || q < 3))
                        out[(size_t)n * SP + spb + p] = z;
                }
        } else {
            // stats on raw acc (invalid positions w=62,63 zeroed: q==3, reg==3, wt>=2)
#pragma unroll
            for (int wt = 0; wt < 4; ++wt)
#pragma unroll
                for (int reg = 0; reg < 4; ++reg) {
                    float a = acc[wt][reg];
                    if ((wt >= 2) && (reg == 3)) a = (q < 3) ? a : 0.f;
                    sS += a; qS = fmaf(a, a, qS);
                }
            if (MODE == 1) {
                const size_t ypd = (size_t)(n * CO + c) * (SP64 / 2)
                                 + (size_t)(d * DOUT + h) * 32 + 8 * q;  // 16B-aligned
                uint4 s0, s1;
                s0.x = pk2(acc[0][0], acc[1][0]); s0.y = pk2(acc[2][0], acc[3][0]);
                s0.z = pk2(acc[0][1], acc[1][1]); s0.w = pk2(acc[2][1], acc[3][1]);
                s1.x = pk2(acc[0][2], acc[1][2]); s1.y = pk2(acc[2][2], acc[3][2]);
                s1.z = pk2(acc[0][3], acc[1][3]); s1.w = pk2(acc[2][3], acc[3][3]);
                *(uint4*)(y32 + ypd)     = s0;
                *(uint4*)(y32 + ypd + 4) = s1;    // w=62,63 land in pad, skipped by pass2
            }
        }
    }

    if (MODE != 2) {
        sS += __shfl_xor(sS, 16); qS += __shfl_xor(qS, 16);
        sS += __shfl_xor(sS, 32); qS += __shfl_xor(qS, 32);
        if (lane < 16) { redS[ty][c] = sS; redQ[ty][c] = qS; }
        __syncthreads();
        if (ty == 0 && lane < 16) {
            float s = 0.f, qq = 0.f;
#pragma unroll
            for (int wv = 0; wv < 8; ++wv) { s += redS[wv][lane]; qq += redQ[wv][lane]; }
            const int blk = blockIdx.y * HT + blockIdx.x;    // 0..495
            g_psum[(n * CO + lane) * NPART + blk] = s;
            g_psq [(n * CO + lane) * NPART + blk] = qq;
        }
    }
}

// Reduce 496 partials per (n,c) -> (A, B'):  z = a*A + B'  (b, m fold out)
__global__ __launch_bounds__(256) void finalize_stats_kernel(const float* __restrict__ m)
{
    const int idx = blockIdx.x;              // n*16 + o
    const int tid = threadIdx.x;
    __shared__ float ls[256], lq[256];
    float s = g_psum[idx * NPART + tid];
    float q = g_psq [idx * NPART + tid];
    if (tid + 256 < NPART) {
        s += g_psum[idx * NPART + tid + 256];
        q += g_psq [idx * NPART + tid + 256];
    }
    ls[tid] = s; lq[tid] = q;
    __syncthreads();
    for (int off = 128; off > 0; off >>= 1) {
        if (tid < off) { ls[tid] += ls[tid + off]; lq[tid] += lq[tid + off]; }
        __syncthreads();
    }
    if (tid == 0) {
        const float inv_n = 1.0f / (float)SP;
        const float muA = ls[0] * inv_n;
        const float varA = fmaxf(lq[0] * inv_n - muA * muA, 0.f);
        const float mo = m[idx & 15];
        const float isv = rsqrtf(fmaf(mo * mo, varA, 1e-5f));
        const float A = mo * isv;
        g_stats[idx * 2 + 0] = A;
        g_stats[idx * 2 + 1] = -muA * A;
    }
}

// Pass 2: y[n][ch][d][h][64] raw-acc bf16; z = a*A+B', clamp, *m, channel-max
__global__ __launch_bounds__(256) void pass2_kernel(
    const unsigned int* __restrict__ y32, const float* __restrict__ m,
    float* __restrict__ out)
{
    const int n = blockIdx.y;
    const int t = blockIdx.x * 256 + threadIdx.x;
    if (t >= DOUT * DOUT * 32) return;
    const int wp = t & 31;
    if (wp == 31) return;                    // pad dword (w=62,63)
    const int row = t >> 5;                  // d*62 + h
    const float* st = g_stats + n * CO * 2;
    const unsigned int* yn = y32 + (size_t)n * CO * (SP64 / 2) + t;
    float mx0 = -FLT_MAX, mx1 = -FLT_MAX;
#pragma unroll
    for (int o = 0; o < CO; ++o) {
        const unsigned int u = yn[(size_t)o * (SP64 / 2)];
        const float a0 = __uint_as_float(u << 16);
        const float a1 = __uint_as_float(u & 0xFFFF0000u);
        const float A = st[o * 2], Bp = st[o * 2 + 1], mo = m[o];
        const float z0 = fminf(fmaxf(fmaf(a0, A, Bp), -1.f), 1.f) * mo;
        const float z1 = fminf(fmaxf(fmaf(a1, A, Bp), -1.f), 1.f) * mo;
        mx0 = fmaxf(mx0, z0); mx1 = fmaxf(mx1, z1);
    }
    const int sp = row * DOUT + 2 * wp;
    *(float2*)(out + (size_t)n * SP + sp) = make_float2(mx0, mx1);
}

extern "C" void kernel_launch(void* const* d_in, const int* in_sizes, int n_in,
                              void* d_out, int out_size, void* d_ws, size_t ws_size,
                              hipStream_t stream)
{
    const float* x = (const float*)d_in[0];
    const float* w = (const float*)d_in[1];
    const float* m = (const float*)d_in[3];
    float* out = (float*)d_out;

    const dim3 blk(64, 8);
    const dim3 grd(HT, DT, NB);
    const size_t yBytes = (size_t)NB * CO * SP64 * 2;   // ~126 MB

    reorg_w_kernel<<<dim3(1), dim3(256), 0, stream>>>(w);

    if (ws_size >= yBytes) {
        unsigned int* y = (unsigned int*)d_ws;
        conv_mfma_kernel<1><<<grd, blk, 0, stream>>>(x, m, y, nullptr);
        finalize_stats_kernel<<<dim3(NB * CO), dim3(256), 0, stream>>>(m);
        pass2_kernel<<<dim3((DOUT * DOUT * 32 + 255) / 256, NB), dim3(256), 0, stream>>>(y, m, out);
    } else {
        conv_mfma_kernel<0><<<grd, blk, 0, stream>>>(x, m, nullptr, nullptr);
        finalize_stats_kernel<<<dim3(NB * CO), dim3(256), 0, stream>>>(m);
        conv_mfma_kernel<2><<<grd, blk, 0, stream>>>(x, m, nullptr, out);
    }
}